// Round 1
// baseline (3815.195 us; speedup 1.0000x reference)
//
#include <hip/hip_runtime.h>
#include <math.h>

#define NND 100000   // nodes
#define NED 200000   // edges
// MEM=172, TD=100, K=10, MSG=616, 3*MEM=516

// ---------------------------------------------------------------- small kernels

__global__ void init_k(int* lastpos, float* relu_sum) {
  int i = blockIdx.x * 256 + threadIdx.x;
  if (i < NND) lastpos[i] = -1;
  if (i < 172) relu_sum[i] = 0.f;
}

__global__ void scatter_k(const int* __restrict__ src, const int* __restrict__ dst,
                          int* lastpos) {
  int e = blockIdx.x * 256 + threadIdx.x;
  if (e < NED) {
    atomicMax(&lastpos[src[e]], e);
    atomicMax(&lastpos[dst[e]], NED + e);
  }
}

__global__ void meta_k(const int* __restrict__ lastpos,
                       const int* __restrict__ src, const int* __restrict__ dst,
                       const float* __restrict__ ts, const float* __restrict__ last_update,
                       int* other, int* edge, float* dtv, int* hasm) {
  int n = blockIdx.x * 256 + threadIdx.x;
  if (n >= NND) return;
  int p = lastpos[n];
  int oth = n, e = 0, hm = 0;
  float d = 0.f;
  if (p >= 0) {
    hm = 1;
    if (p >= NED) { e = p - NED; oth = src[e]; }   // node was destination
    else          { e = p;       oth = dst[e]; }   // node was source
    d = ts[e] - last_update[n];
  }
  other[n] = oth; edge[n] = e; dtv[n] = d; hasm[n] = hm;
}

__global__ void qbias_k(const float* __restrict__ tb, const float* __restrict__ Wq,
                        float* qbias) {
  int o = threadIdx.x;
  if (o < 172) {
    float s = 0.f;
    for (int d = 0; d < 100; d++) s += cosf(tb[d]) * Wq[(172 + d) * 172 + o];
    qbias[o] = s;
  }
}

__global__ void gru_k(const float* __restrict__ gi, const float* __restrict__ gh,
                      const float* __restrict__ memory, const float* __restrict__ nf,
                      const int* __restrict__ hasm, float* h) {
  int i = blockIdx.x * 256 + threadIdx.x;
  if (i >= NND * 172) return;
  int n = i / 172, c = i - n * 172;
  float memv = memory[i];
  float hv = memv;
  if (hasm[n]) {
    const float* gin = gi + (size_t)n * 516;
    const float* ghn = gh + (size_t)n * 516;
    float r  = 1.f / (1.f + expf(-(gin[c]       + ghn[c])));
    float z  = 1.f / (1.f + expf(-(gin[172 + c] + ghn[172 + c])));
    float nn = tanhf(gin[344 + c] + r * ghn[344 + c]);
    hv = (1.f - z) * nn + z * memv;
  }
  h[i] = hv + nf[i];
}

// ---------------------------------------------------------------- generic f32 GEMM
// C[M,O] = A[M,K] @ B + bias.  AMODE: 0 plain A; 1 message gather; 2 concat(h,agg).
// BT: 1 -> B stored [O,K] (Linear weight); 0 -> B stored [K,O].
// EPI: 0 -> store C; 1 -> relu + column-sum (excluding row 0) atomically into red.

struct GArgs {
  const float* A; const float* A2;
  const float* ef; const float* tw; const float* tb;
  const int* other; const int* edge; const float* dt;
  const float* B; const float* bias;
  float* C; float* red;
  int M, K, O;
};

constexpr int LSTR = 68;  // padded LDS row stride (floats): 16B-aligned rows, <=2-way banks

template<int AMODE, int BT, int EPI>
__global__ __launch_bounds__(256) void gemm_k(GArgs g) {
  __shared__ __align__(16) float As[16 * LSTR];
  __shared__ __align__(16) float Bs[16 * LSTR];
  __shared__ float Rs[16 * 64];
  const int tid = threadIdx.x;
  const int m0 = blockIdx.x * 64, o0 = blockIdx.y * 64;
  const int ty = tid >> 4, tx = tid & 15;
  const int lm = tid >> 2, lk = (tid & 3) * 4;
  float acc[4][4] = {};
  for (int k0 = 0; k0 < g.K; k0 += 16) {
    // ---- A tile (64 rows x 16 k), stored transposed As[k][m]
    {
      float4 av = {0.f, 0.f, 0.f, 0.f};
      const int m = m0 + lm, k = k0 + lk;
      if (m < g.M && k < g.K) {
        if (AMODE == 0) {
          av = *(const float4*)(g.A + (size_t)m * g.K + k);
        } else if (AMODE == 1) {
          if (k < 172)      av = *(const float4*)(g.A + (size_t)m * 172 + k);
          else if (k < 344) av = *(const float4*)(g.A + (size_t)g.other[m] * 172 + (k - 172));
          else if (k < 516) av = *(const float4*)(g.ef + (size_t)g.edge[m] * 172 + (k - 344));
          else {
            const float d = g.dt[m];
            float t0 = cosf(d * g.tw[k - 516 + 0] + g.tb[k - 516 + 0]);
            float t1 = cosf(d * g.tw[k - 516 + 1] + g.tb[k - 516 + 1]);
            float t2 = cosf(d * g.tw[k - 516 + 2] + g.tb[k - 516 + 2]);
            float t3 = cosf(d * g.tw[k - 516 + 3] + g.tb[k - 516 + 3]);
            av.x = t0; av.y = t1; av.z = t2; av.w = t3;
          }
        } else {
          av = (k < 172) ? *(const float4*)(g.A + (size_t)m * 172 + k)
                         : *(const float4*)(g.A2 + (size_t)m * 172 + (k - 172));
        }
      }
      As[(lk + 0) * LSTR + lm] = av.x;
      As[(lk + 1) * LSTR + lm] = av.y;
      As[(lk + 2) * LSTR + lm] = av.z;
      As[(lk + 3) * LSTR + lm] = av.w;
    }
    // ---- B tile (16 k x 64 o), stored Bs[k][o]
    if (BT == 1) {
      float4 bv = {0.f, 0.f, 0.f, 0.f};
      const int o = o0 + lm, k = k0 + lk;
      if (o < g.O && k < g.K) bv = *(const float4*)(g.B + (size_t)o * g.K + k);
      Bs[(lk + 0) * LSTR + lm] = bv.x;
      Bs[(lk + 1) * LSTR + lm] = bv.y;
      Bs[(lk + 2) * LSTR + lm] = bv.z;
      Bs[(lk + 3) * LSTR + lm] = bv.w;
    } else {
      const int kk = tid >> 4, ol = (tid & 15) * 4;
      float4 bv = {0.f, 0.f, 0.f, 0.f};
      const int kg = k0 + kk, o = o0 + ol;
      if (kg < g.K && o < g.O) bv = *(const float4*)(g.B + (size_t)kg * g.O + o);
      *(float4*)&Bs[kk * LSTR + ol] = bv;
    }
    __syncthreads();
    #pragma unroll
    for (int kk = 0; kk < 16; kk++) {
      const float4 a4 = *(const float4*)&As[kk * LSTR + ty * 4];
      const float4 b4 = *(const float4*)&Bs[kk * LSTR + tx * 4];
      const float ar[4] = {a4.x, a4.y, a4.z, a4.w};
      const float br[4] = {b4.x, b4.y, b4.z, b4.w};
      #pragma unroll
      for (int i = 0; i < 4; i++)
        #pragma unroll
        for (int j = 0; j < 4; j++)
          acc[i][j] = fmaf(ar[i], br[j], acc[i][j]);
    }
    __syncthreads();
  }
  if (EPI == 0) {
    #pragma unroll
    for (int i = 0; i < 4; i++) {
      const int m = m0 + ty * 4 + i;
      if (m < g.M) {
        #pragma unroll
        for (int j = 0; j < 4; j++) {
          const int o = o0 + tx * 4 + j;
          if (o < g.O) {
            const float bj = g.bias ? g.bias[o] : 0.f;
            g.C[(size_t)m * g.O + o] = acc[i][j] + bj;
          }
        }
      }
    }
  } else {
    float colp[4] = {0.f, 0.f, 0.f, 0.f};
    #pragma unroll
    for (int i = 0; i < 4; i++) {
      const int m = m0 + ty * 4 + i;
      const bool valid = (m < g.M) && (m != 0);   // mean skips padding node 0
      #pragma unroll
      for (int j = 0; j < 4; j++) {
        const int o = o0 + tx * 4 + j;
        if (o < g.O && valid) colp[j] += fmaxf(acc[i][j] + g.bias[o], 0.f);
      }
    }
    #pragma unroll
    for (int j = 0; j < 4; j++) Rs[ty * 64 + tx * 4 + j] = colp[j];
    __syncthreads();
    if (tid < 64) {
      const int o = o0 + tid;
      if (o < g.O) {
        float s = 0.f;
        for (int r = 0; r < 16; r++) s += Rs[r * 64 + tid];
        atomicAdd(&g.red[o], s);
      }
    }
  }
}

// ---------------------------------------------------------------- attention (1 block / node)
// scores decomposed:  q.k = q.hk[idx] + tenc . (Wk2^T q_head)
// agg   decomposed:   sum_j a_j v_j = sum_j a_j hv[idx_j] + (sum_j a_j tenc_j) @ Wv2

__global__ __launch_bounds__(192) void attn_k(
    const float* __restrict__ qv, const float* __restrict__ hk, const float* __restrict__ hv,
    const float* __restrict__ Wk2, const float* __restrict__ Wv2,
    const float* __restrict__ tw, const float* __restrict__ tb,
    const int* __restrict__ nidx, const float* __restrict__ nts,
    const float* __restrict__ ts, float* __restrict__ agg) {
  __shared__ float qbuf[172];
  __shared__ float tencs[10][100];
  __shared__ float qkt[2][100];
  __shared__ float sc[2][10];
  __shared__ float attw[2][10];
  __shared__ float wt[2][100];
  __shared__ float hkb[10][172];
  __shared__ float hvb[10][172];
  __shared__ int   nix[10];
  __shared__ float ndt[10];
  const int n = blockIdx.x;
  const int t = threadIdx.x;
  const float t_now = ts[NED - 1];
  if (t < 172) qbuf[t] = qv[(size_t)n * 172 + t];
  if (t >= 172 && t < 182) {
    int j = t - 172;
    nix[j] = nidx[n * 10 + j];
    ndt[j] = t_now - nts[n * 10 + j];
  }
  __syncthreads();
  for (int l = t; l < 1000; l += 192) {
    int j = l / 100, d = l - j * 100;
    tencs[j][d] = cosf(ndt[j] * tw[d] + tb[d]);
  }
  for (int l = t; l < 1720; l += 192) {
    int j = l / 172, c = l - j * 172;
    int ix = nix[j];
    hkb[j][c] = hk[(size_t)ix * 172 + c];
    hvb[j][c] = hv[(size_t)ix * 172 + c];
  }
  __syncthreads();
  for (int l = t; l < 200; l += 192) {
    int hh = l / 100, d = l - hh * 100;
    const float* wrow = Wk2 + d * 172 + hh * 86;
    const float* qrow = qbuf + hh * 86;
    float s = 0.f;
    for (int c = 0; c < 86; c++) s = fmaf(wrow[c], qrow[c], s);
    qkt[hh][d] = s;
  }
  __syncthreads();
  if (t < 20) {
    int hh = t / 10, j = t - hh * 10;
    float s = 0.f;
    for (int c = 0; c < 86; c++) s = fmaf(hkb[j][hh * 86 + c], qbuf[hh * 86 + c], s);
    for (int d = 0; d < 100; d++) s = fmaf(tencs[j][d], qkt[hh][d], s);
    sc[hh][j] = s * (1.0f / sqrtf(86.0f));
  }
  __syncthreads();
  if (t < 2) {
    float m = sc[t][0];
    for (int j = 1; j < 10; j++) m = fmaxf(m, sc[t][j]);
    float sum = 0.f;
    float e[10];
    for (int j = 0; j < 10; j++) { e[j] = expf(sc[t][j] - m); sum += e[j]; }
    float inv = 1.f / sum;
    for (int j = 0; j < 10; j++) attw[t][j] = e[j] * inv;
  }
  __syncthreads();
  for (int l = t; l < 200; l += 192) {
    int hh = l / 100, d = l - hh * 100;
    float s = 0.f;
    for (int j = 0; j < 10; j++) s = fmaf(attw[hh][j], tencs[j][d], s);
    wt[hh][d] = s;
  }
  __syncthreads();
  if (t < 172) {
    int hh = t / 86;
    float a = 0.f;
    for (int j = 0; j < 10; j++) a = fmaf(attw[hh][j], hvb[j][t], a);
    for (int d = 0; d < 100; d++) a = fmaf(wt[hh][d], Wv2[d * 172 + t], a);
    agg[(size_t)n * 172 + t] = a;
  }
}

// ---------------------------------------------------------------- classifier head

__global__ void head_k(const float* __restrict__ relu_sum, const float* __restrict__ W2,
                       const float* __restrict__ b2, const float* __restrict__ fc2w,
                       const float* __restrict__ fc2b, float* out) {
  __shared__ float th[172];
  int t = threadIdx.x;
  if (t < 172) {
    float s = 0.f;
    for (int c = 0; c < 172; c++) s = fmaf(relu_sum[c], W2[c * 172 + t], s);
    s = s * (1.0f / 99999.0f) + b2[t];
    th[t] = tanhf(s);
  }
  __syncthreads();
  if (t == 0) {
    float l0 = fc2b[0], l1 = fc2b[1];
    for (int o = 0; o < 172; o++) {
      l0 = fmaf(th[o], fc2w[o * 2 + 0], l0);
      l1 = fmaf(th[o], fc2w[o * 2 + 1], l1);
    }
    float mx = fmaxf(l0, l1);
    float e0 = expf(l0 - mx), e1 = expf(l1 - mx);
    float inv = 1.f / (e0 + e1);
    out[0] = e0 * inv;
    out[1] = e1 * inv;
  }
}

// ---------------------------------------------------------------- launch

extern "C" void kernel_launch(void* const* d_in, const int* in_sizes, int n_in,
                              void* d_out, int out_size, void* d_ws, size_t ws_size,
                              hipStream_t stream) {
  (void)in_sizes; (void)n_in; (void)out_size;
  const float* node_features = (const float*)d_in[0];
  const float* memory        = (const float*)d_in[1];
  const float* last_update   = (const float*)d_in[2];
  const float* timestamps    = (const float*)d_in[3];
  const float* edge_features = (const float*)d_in[4];
  const float* neighbor_ts   = (const float*)d_in[5];
  const float* time_w        = (const float*)d_in[6];
  const float* time_b        = (const float*)d_in[7];
  const float* gru_Wi        = (const float*)d_in[8];
  const float* gru_Wh        = (const float*)d_in[9];
  const float* gru_bi        = (const float*)d_in[10];
  const float* gru_bh        = (const float*)d_in[11];
  const float* Wq            = (const float*)d_in[12];
  const float* Wk            = (const float*)d_in[13];
  const float* Wv            = (const float*)d_in[14];
  const float* W1            = (const float*)d_in[15];
  const float* b1            = (const float*)d_in[16];
  const float* W2            = (const float*)d_in[17];
  const float* b2            = (const float*)d_in[18];
  const float* fc2_w         = (const float*)d_in[19];
  const float* fc2_b         = (const float*)d_in[20];
  const int* sources         = (const int*)d_in[21];
  const int* destinations    = (const int*)d_in[22];
  const int* neighbor_idx    = (const int*)d_in[23];
  float* out = (float*)d_out;

  // workspace layout (4-byte words), regions aliased by lifetime
  float* F = (float*)d_ws;
  int*   I = (int*)d_ws;
  size_t off = 0;
  auto alloc = [&off](size_t words) { size_t r = off; off += (words + 63) & ~(size_t)63; return r; };
  const size_t w_lastpos = alloc(NND);
  const size_t w_other   = alloc(NND);
  const size_t w_edge    = alloc(NND);
  const size_t w_dtv     = alloc(NND);
  const size_t w_hasm    = alloc(NND);
  const size_t w_qbias   = alloc(172);
  const size_t w_relu    = alloc(172);
  const size_t w_h       = alloc((size_t)NND * 172);
  const size_t w_R1      = alloc((size_t)NND * 516);  // gi, then {q,hk,hv}
  const size_t w_R2      = alloc((size_t)NND * 516);  // gh, then agg
  if (ws_size < off * 4) return;  // insufficient scratch -> visible failure

  int*   lastpos = I + w_lastpos;
  int*   other   = I + w_other;
  int*   edge    = I + w_edge;
  float* dtv     = F + w_dtv;
  int*   hasm    = I + w_hasm;
  float* qbias   = F + w_qbias;
  float* relu_s  = F + w_relu;
  float* h       = F + w_h;
  float* gi      = F + w_R1;
  float* gh      = F + w_R2;
  float* qg      = F + w_R1;                          // aliases gi (dead)
  float* hkg     = F + w_R1 + (size_t)NND * 172;
  float* hvg     = F + w_R1 + (size_t)NND * 172 * 2;
  float* aggg    = F + w_R2;                          // aliases gh (dead)

  const int MB = (NND + 63) / 64;  // 1563

  init_k<<<(NND + 255) / 256, 256, 0, stream>>>(lastpos, relu_s);
  scatter_k<<<(NED + 255) / 256, 256, 0, stream>>>(sources, destinations, lastpos);
  meta_k<<<(NND + 255) / 256, 256, 0, stream>>>(lastpos, sources, destinations,
                                                timestamps, last_update,
                                                other, edge, dtv, hasm);
  qbias_k<<<1, 256, 0, stream>>>(time_b, Wq, qbias);

  {  // gi = msg @ Wi^T + bi   (message gathered on the fly)
    GArgs g = {memory, nullptr, edge_features, time_w, time_b, other, edge, dtv,
               gru_Wi, gru_bi, gi, nullptr, NND, 616, 516};
    gemm_k<1, 1, 0><<<dim3(MB, 9), 256, 0, stream>>>(g);
  }
  {  // gh = memory @ Wh^T + bh
    GArgs g = {memory, nullptr, nullptr, nullptr, nullptr, nullptr, nullptr, nullptr,
               gru_Wh, gru_bh, gh, nullptr, NND, 172, 516};
    gemm_k<0, 1, 0><<<dim3(MB, 9), 256, 0, stream>>>(g);
  }
  gru_k<<<((size_t)NND * 172 + 255) / 256, 256, 0, stream>>>(gi, gh, memory,
                                                             node_features, hasm, h);
  {  // q = h @ Wq[:172] + qbias
    GArgs g = {h, nullptr, nullptr, nullptr, nullptr, nullptr, nullptr, nullptr,
               Wq, qbias, qg, nullptr, NND, 172, 172};
    gemm_k<0, 0, 0><<<dim3(MB, 3), 256, 0, stream>>>(g);
  }
  {  // hk = h @ Wk[:172]
    GArgs g = {h, nullptr, nullptr, nullptr, nullptr, nullptr, nullptr, nullptr,
               Wk, nullptr, hkg, nullptr, NND, 172, 172};
    gemm_k<0, 0, 0><<<dim3(MB, 3), 256, 0, stream>>>(g);
  }
  {  // hv = h @ Wv[:172]
    GArgs g = {h, nullptr, nullptr, nullptr, nullptr, nullptr, nullptr, nullptr,
               Wv, nullptr, hvg, nullptr, NND, 172, 172};
    gemm_k<0, 0, 0><<<dim3(MB, 3), 256, 0, stream>>>(g);
  }
  attn_k<<<NND, 192, 0, stream>>>(qg, hkg, hvg, Wk + 172 * 172, Wv + 172 * 172,
                                  time_w, time_b, neighbor_idx, neighbor_ts,
                                  timestamps, aggg);
  {  // relu_sum += sum over nodes!=0 of relu([h|agg] @ W1 + b1)
    GArgs g = {h, aggg, nullptr, nullptr, nullptr, nullptr, nullptr, nullptr,
               W1, b1, nullptr, relu_s, NND, 344, 172};
    gemm_k<2, 0, 1><<<dim3(MB, 3), 256, 0, stream>>>(g);
  }
  head_k<<<1, 256, 0, stream>>>(relu_s, W2, b2, fc2_w, fc2_b, out);
}

// Round 2
// 3445.182 us; speedup vs baseline: 1.1074x; 1.1074x over previous
//
#include <hip/hip_runtime.h>
#include <math.h>

#define NND 100000   // nodes
#define NED 200000   // edges
// MEM=172, TD=100, K=10, MSG=616, 3*MEM=516

// ---------------------------------------------------------------- small kernels

__global__ void init_k(int* lastpos, float* relu_sum) {
  int i = blockIdx.x * 256 + threadIdx.x;
  if (i < NND) lastpos[i] = -1;
  if (i < 172) relu_sum[i] = 0.f;
}

__global__ void scatter_k(const int* __restrict__ src, const int* __restrict__ dst,
                          int* lastpos) {
  int e = blockIdx.x * 256 + threadIdx.x;
  if (e < NED) {
    atomicMax(&lastpos[src[e]], e);
    atomicMax(&lastpos[dst[e]], NED + e);
  }
}

__global__ void meta_k(const int* __restrict__ lastpos,
                       const int* __restrict__ src, const int* __restrict__ dst,
                       const float* __restrict__ ts, const float* __restrict__ last_update,
                       int* other, int* edge, float* dtv, int* hasm) {
  int n = blockIdx.x * 256 + threadIdx.x;
  if (n >= NND) return;
  int p = lastpos[n];
  int oth = n, e = 0, hm = 0;
  float d = 0.f;
  if (p >= 0) {
    hm = 1;
    if (p >= NED) { e = p - NED; oth = src[e]; }   // node was destination
    else          { e = p;       oth = dst[e]; }   // node was source
    d = ts[e] - last_update[n];
  }
  other[n] = oth; edge[n] = e; dtv[n] = d; hasm[n] = hm;
}

__global__ void qbias_k(const float* __restrict__ tb, const float* __restrict__ Wq,
                        float* qbias) {
  int o = threadIdx.x;
  if (o < 172) {
    float s = 0.f;
    for (int d = 0; d < 100; d++) s += cosf(tb[d]) * Wq[(172 + d) * 172 + o];
    qbias[o] = s;
  }
}

// packed B for the fused projection GEMM: [172 x 716] = [Wq | Wk | Wv | Wqk2]
// Wqk2[c][(h,d)] = sum_{c'<86} Wq[c][h*86+c'] * Wk[172+d][h*86+c']
__global__ void packB_k(const float* __restrict__ Wq, const float* __restrict__ Wk,
                        const float* __restrict__ Wv, float* B) {
  int i = blockIdx.x * 256 + threadIdx.x;
  if (i >= 172 * 716) return;
  int c = i / 716, o = i - c * 716;
  float v;
  if (o < 172)      v = Wq[c * 172 + o];
  else if (o < 344) v = Wk[c * 172 + (o - 172)];
  else if (o < 516) v = Wv[c * 172 + (o - 344)];
  else {
    int p = o - 516, hh = p / 100, d = p - hh * 100;
    const float* wq  = Wq + c * 172 + hh * 86;
    const float* wk2 = Wk + (172 + d) * 172 + hh * 86;
    float s = 0.f;
    for (int cc = 0; cc < 86; cc++) s = fmaf(wq[cc], wk2[cc], s);
    v = s;
  }
  B[i] = v;
}

// bias for the 716 output cols: [qbias | 0 | 0 | qk2-const]
__global__ void bias716_k(const float* __restrict__ qbias, const float* __restrict__ Wk,
                          float* bias) {
  int o = blockIdx.x * 256 + threadIdx.x;
  if (o >= 716) return;
  float v = 0.f;
  if (o < 172) v = qbias[o];
  else if (o >= 516) {
    int p = o - 516, hh = p / 100, d = p - hh * 100;
    const float* qb  = qbias + hh * 86;
    const float* wk2 = Wk + (172 + d) * 172 + hh * 86;
    float s = 0.f;
    for (int cc = 0; cc < 86; cc++) s = fmaf(qb[cc], wk2[cc], s);
    v = s;
  }
  bias[o] = v;
}

__global__ void gru_k(const float* __restrict__ gi, const float* __restrict__ gh,
                      const float* __restrict__ memory, const float* __restrict__ nf,
                      const int* __restrict__ hasm, float* h) {
  int i = blockIdx.x * 256 + threadIdx.x;
  if (i >= NND * 172) return;
  int n = i / 172, c = i - n * 172;
  float memv = memory[i];
  float hv = memv;
  if (hasm[n]) {
    const float* gin = gi + (size_t)n * 516;
    const float* ghn = gh + (size_t)n * 516;
    float r  = 1.f / (1.f + expf(-(gin[c]       + ghn[c])));
    float z  = 1.f / (1.f + expf(-(gin[172 + c] + ghn[172 + c])));
    float nn = tanhf(gin[344 + c] + r * ghn[344 + c]);
    hv = (1.f - z) * nn + z * memv;
  }
  h[i] = hv + nf[i];
}

// ---------------------------------------------------------------- generic f32 GEMM
// C[M,O] = A[M,K] @ B + bias.  AMODE: 0 plain A; 1 message gather; 2 concat(h,agg).
// BT: 1 -> B stored [O,K] (Linear weight); 0 -> B stored [K,O].
// EPI: 0 -> store C; 1 -> relu + column-sum (excluding row 0) atomically into red.

struct GArgs {
  const float* A; const float* A2;
  const float* ef; const float* tw; const float* tb;
  const int* other; const int* edge; const float* dt;
  const float* B; const float* bias;
  float* C; float* red;
  int M, K, O;
};

constexpr int LSTR = 68;  // padded LDS row stride (floats)

template<int AMODE, int BT, int EPI>
__global__ __launch_bounds__(256) void gemm_k(GArgs g) {
  __shared__ __align__(16) float As[16 * LSTR];
  __shared__ __align__(16) float Bs[16 * LSTR];
  __shared__ float Rs[16 * 64];
  const int tid = threadIdx.x;
  const int m0 = blockIdx.x * 64, o0 = blockIdx.y * 64;
  const int ty = tid >> 4, tx = tid & 15;
  const int lm = tid >> 2, lk = (tid & 3) * 4;
  float acc[4][4] = {};
  for (int k0 = 0; k0 < g.K; k0 += 16) {
    // ---- A tile (64 rows x 16 k), stored transposed As[k][m]
    {
      float4 av = {0.f, 0.f, 0.f, 0.f};
      const int m = m0 + lm, k = k0 + lk;
      if (m < g.M && k < g.K) {
        if (AMODE == 0) {
          av = *(const float4*)(g.A + (size_t)m * g.K + k);
        } else if (AMODE == 1) {
          if (k < 172)      av = *(const float4*)(g.A + (size_t)m * 172 + k);
          else if (k < 344) av = *(const float4*)(g.A + (size_t)g.other[m] * 172 + (k - 172));
          else if (k < 516) av = *(const float4*)(g.ef + (size_t)g.edge[m] * 172 + (k - 344));
          else {
            const float d = g.dt[m];
            av.x = cosf(d * g.tw[k - 516 + 0] + g.tb[k - 516 + 0]);
            av.y = cosf(d * g.tw[k - 516 + 1] + g.tb[k - 516 + 1]);
            av.z = cosf(d * g.tw[k - 516 + 2] + g.tb[k - 516 + 2]);
            av.w = cosf(d * g.tw[k - 516 + 3] + g.tb[k - 516 + 3]);
          }
        } else {
          av = (k < 172) ? *(const float4*)(g.A + (size_t)m * 172 + k)
                         : *(const float4*)(g.A2 + (size_t)m * 172 + (k - 172));
        }
      }
      As[(lk + 0) * LSTR + lm] = av.x;
      As[(lk + 1) * LSTR + lm] = av.y;
      As[(lk + 2) * LSTR + lm] = av.z;
      As[(lk + 3) * LSTR + lm] = av.w;
    }
    // ---- B tile (16 k x 64 o), stored Bs[k][o]
    if (BT == 1) {
      float4 bv = {0.f, 0.f, 0.f, 0.f};
      const int o = o0 + lm, k = k0 + lk;
      if (o < g.O && k < g.K) bv = *(const float4*)(g.B + (size_t)o * g.K + k);
      Bs[(lk + 0) * LSTR + lm] = bv.x;
      Bs[(lk + 1) * LSTR + lm] = bv.y;
      Bs[(lk + 2) * LSTR + lm] = bv.z;
      Bs[(lk + 3) * LSTR + lm] = bv.w;
    } else {
      const int kk = tid >> 4, ol = (tid & 15) * 4;
      float4 bv = {0.f, 0.f, 0.f, 0.f};
      const int kg = k0 + kk, o = o0 + ol;
      if (kg < g.K && o < g.O) bv = *(const float4*)(g.B + (size_t)kg * g.O + o);
      *(float4*)&Bs[kk * LSTR + ol] = bv;
    }
    __syncthreads();
    #pragma unroll
    for (int kk = 0; kk < 16; kk++) {
      const float4 a4 = *(const float4*)&As[kk * LSTR + ty * 4];
      const float4 b4 = *(const float4*)&Bs[kk * LSTR + tx * 4];
      const float ar[4] = {a4.x, a4.y, a4.z, a4.w};
      const float br[4] = {b4.x, b4.y, b4.z, b4.w};
      #pragma unroll
      for (int i = 0; i < 4; i++)
        #pragma unroll
        for (int j = 0; j < 4; j++)
          acc[i][j] = fmaf(ar[i], br[j], acc[i][j]);
    }
    __syncthreads();
  }
  if (EPI == 0) {
    #pragma unroll
    for (int i = 0; i < 4; i++) {
      const int m = m0 + ty * 4 + i;
      if (m < g.M) {
        #pragma unroll
        for (int j = 0; j < 4; j++) {
          const int o = o0 + tx * 4 + j;
          if (o < g.O) {
            const float bj = g.bias ? g.bias[o] : 0.f;
            g.C[(size_t)m * g.O + o] = acc[i][j] + bj;
          }
        }
      }
    }
  } else {
    float colp[4] = {0.f, 0.f, 0.f, 0.f};
    #pragma unroll
    for (int i = 0; i < 4; i++) {
      const int m = m0 + ty * 4 + i;
      const bool valid = (m < g.M) && (m != 0);   // mean skips padding node 0
      #pragma unroll
      for (int j = 0; j < 4; j++) {
        const int o = o0 + tx * 4 + j;
        if (o < g.O && valid) colp[j] += fmaxf(acc[i][j] + g.bias[o], 0.f);
      }
    }
    #pragma unroll
    for (int j = 0; j < 4; j++) Rs[ty * 64 + tx * 4 + j] = colp[j];
    __syncthreads();
    if (tid < 64) {
      const int o = o0 + tid;
      if (o < g.O) {
        float s = 0.f;
        for (int r = 0; r < 16; r++) s += Rs[r * 64 + tid];
        atomicAdd(&g.red[o], s);
      }
    }
  }
}

// ---------------------------------------------------------------- attention v2
// One wave (64 lanes) per node, 4 nodes per 256-thread block. Barrier-free
// except one cheap __syncthreads for the LDS wt broadcast.
// C row layout per node: [ q(172) | hk(172) | hv(172) | qk2(2x100) ]
// score[h][j] = ( q . hk[idx_j] (head h part) + tenc_j . qk2[h] ) / sqrt(86)
// agg[t]     = sum_j a[h(t)][j] * hv[idx_j][t]  +  sum_d wt[h(t)][d] * Wv2[d][t]
//   where wt[h][d] = sum_j a[h][j] * tenc_j[d]
__global__ __launch_bounds__(256) void attn2_k(
    const float* __restrict__ C,
    const float* __restrict__ Wv,                 // rows 172.. are Wv2
    const float* __restrict__ tw, const float* __restrict__ tb,
    const int* __restrict__ nidx, const float* __restrict__ nts,
    const float* __restrict__ ts, float* __restrict__ agg) {
  __shared__ float wts[4][200];
  const int w = threadIdx.x >> 6;
  const int wid = blockIdx.x * 4 + w;
  const int lane = threadIdx.x & 63;
  const float t_now = ts[NED - 1];
  const float* row = C + (size_t)wid * 716;

  const float q0 = row[lane];                               // c=lane        head0
  const float q1 = row[64 + lane];                          // c=64+lane     head = lane<22 ? 0 : 1
  const float q2 = (lane < 44) ? row[128 + lane] : 0.f;     // c=128+lane    head1
  const float k0a = row[516 + lane];
  const float k0b = (lane < 36) ? row[580 + lane] : 0.f;
  const float k1a = row[616 + lane];
  const float k1b = (lane < 36) ? row[680 + lane] : 0.f;
  const float twa = tw[lane], tba = tb[lane];
  const float twb = (lane < 36) ? tw[64 + lane] : 0.f;
  const float tbb = (lane < 36) ? tb[64 + lane] : 0.f;

  float va[10], vb[10], vc[10], ta[10], tbv[10], s0[10], s1[10];
  #pragma unroll
  for (int j = 0; j < 10; j++) {
    const int ix = nidx[wid * 10 + j];
    const float ndt = t_now - nts[wid * 10 + j];
    const float tja = cosf(ndt * twa + tba);
    const float tjb = (lane < 36) ? cosf(ndt * twb + tbb) : 0.f;
    ta[j] = tja; tbv[j] = tjb;
    const float* krow = C + (size_t)ix * 716 + 172;
    const float h0 = krow[lane];
    const float h1 = krow[64 + lane];
    const float h2 = (lane < 44) ? krow[128 + lane] : 0.f;
    const float* vrow = C + (size_t)ix * 716 + 344;
    va[j] = vrow[lane];
    vb[j] = vrow[64 + lane];
    vc[j] = (lane < 44) ? vrow[128 + lane] : 0.f;
    float p0 = q0 * h0 + tja * k0a + tjb * k0b;
    float p1 = q2 * h2 + tja * k1a + tjb * k1b;
    const float m1 = q1 * h1;
    if (lane < 22) p0 += m1; else p1 += m1;
    #pragma unroll
    for (int off = 32; off; off >>= 1) {
      p0 += __shfl_xor(p0, off);
      p1 += __shfl_xor(p1, off);
    }
    const float scale = 0.10783277320343841f;  // 1/sqrt(86)
    s0[j] = p0 * scale; s1[j] = p1 * scale;
  }
  // softmax per head (computed redundantly on every lane, all in registers)
  float m0 = s0[0], m1v = s1[0];
  #pragma unroll
  for (int j = 1; j < 10; j++) { m0 = fmaxf(m0, s0[j]); m1v = fmaxf(m1v, s1[j]); }
  float z0 = 0.f, z1 = 0.f;
  #pragma unroll
  for (int j = 0; j < 10; j++) {
    s0[j] = expf(s0[j] - m0);  z0 += s0[j];
    s1[j] = expf(s1[j] - m1v); z1 += s1[j];
  }
  const float i0 = 1.f / z0, i1 = 1.f / z1;
  float o0 = 0.f, o1 = 0.f, o2 = 0.f;
  float w0a = 0.f, w0b = 0.f, w1a = 0.f, w1b = 0.f;
  #pragma unroll
  for (int j = 0; j < 10; j++) {
    const float a0 = s0[j] * i0, a1 = s1[j] * i1;
    o0 += a0 * va[j];
    o1 += ((lane < 22) ? a0 : a1) * vb[j];
    o2 += a1 * vc[j];
    w0a += a0 * ta[j]; w0b += a0 * tbv[j];
    w1a += a1 * ta[j]; w1b += a1 * tbv[j];
  }
  // broadcast wt through LDS (per-wave slice)
  wts[w][lane] = w0a;
  if (lane < 36) wts[w][64 + lane] = w0b;
  wts[w][100 + lane] = w1a;
  if (lane < 36) wts[w][164 + lane] = w1b;
  __syncthreads();
  // + wt @ Wv2 (Wv2 = rows 172.. of Wv); LDS reads are same-address broadcasts
  #pragma unroll 4
  for (int d = 0; d < 100; d++) {
    const float wv0 = wts[w][d], wv1 = wts[w][100 + d];
    const float* vr = Wv + (size_t)(172 + d) * 172;
    o0 = fmaf(wv0, vr[lane], o0);
    o1 = fmaf((lane < 22) ? wv0 : wv1, vr[64 + lane], o1);
    if (lane < 44) o2 = fmaf(wv1, vr[128 + lane], o2);
  }
  float* orow = agg + (size_t)wid * 172;
  orow[lane] = o0;
  orow[64 + lane] = o1;
  if (lane < 44) orow[128 + lane] = o2;
}

// ---------------------------------------------------------------- classifier head

__global__ void head_k(const float* __restrict__ relu_sum, const float* __restrict__ W2,
                       const float* __restrict__ b2, const float* __restrict__ fc2w,
                       const float* __restrict__ fc2b, float* out) {
  __shared__ float th[172];
  int t = threadIdx.x;
  if (t < 172) {
    float s = 0.f;
    for (int c = 0; c < 172; c++) s = fmaf(relu_sum[c], W2[c * 172 + t], s);
    s = s * (1.0f / 99999.0f) + b2[t];
    th[t] = tanhf(s);
  }
  __syncthreads();
  if (t == 0) {
    float l0 = fc2b[0], l1 = fc2b[1];
    for (int o = 0; o < 172; o++) {
      l0 = fmaf(th[o], fc2w[o * 2 + 0], l0);
      l1 = fmaf(th[o], fc2w[o * 2 + 1], l1);
    }
    float mx = fmaxf(l0, l1);
    float e0 = expf(l0 - mx), e1 = expf(l1 - mx);
    float inv = 1.f / (e0 + e1);
    out[0] = e0 * inv;
    out[1] = e1 * inv;
  }
}

// ---------------------------------------------------------------- launch

extern "C" void kernel_launch(void* const* d_in, const int* in_sizes, int n_in,
                              void* d_out, int out_size, void* d_ws, size_t ws_size,
                              hipStream_t stream) {
  (void)in_sizes; (void)n_in; (void)out_size;
  const float* node_features = (const float*)d_in[0];
  const float* memory        = (const float*)d_in[1];
  const float* last_update   = (const float*)d_in[2];
  const float* timestamps    = (const float*)d_in[3];
  const float* edge_features = (const float*)d_in[4];
  const float* neighbor_ts   = (const float*)d_in[5];
  const float* time_w        = (const float*)d_in[6];
  const float* time_b        = (const float*)d_in[7];
  const float* gru_Wi        = (const float*)d_in[8];
  const float* gru_Wh        = (const float*)d_in[9];
  const float* gru_bi        = (const float*)d_in[10];
  const float* gru_bh        = (const float*)d_in[11];
  const float* Wq            = (const float*)d_in[12];
  const float* Wk            = (const float*)d_in[13];
  const float* Wv            = (const float*)d_in[14];
  const float* W1            = (const float*)d_in[15];
  const float* b1            = (const float*)d_in[16];
  const float* W2            = (const float*)d_in[17];
  const float* b2            = (const float*)d_in[18];
  const float* fc2_w         = (const float*)d_in[19];
  const float* fc2_b         = (const float*)d_in[20];
  const int* sources         = (const int*)d_in[21];
  const int* destinations    = (const int*)d_in[22];
  const int* neighbor_idx    = (const int*)d_in[23];
  float* out = (float*)d_out;

  // workspace layout (4-byte words), regions aliased by lifetime
  float* F = (float*)d_ws;
  int*   I = (int*)d_ws;
  size_t off = 0;
  auto alloc = [&off](size_t words) { size_t r = off; off += (words + 63) & ~(size_t)63; return r; };
  const size_t w_lastpos = alloc(NND);
  const size_t w_other   = alloc(NND);
  const size_t w_edge    = alloc(NND);
  const size_t w_dtv     = alloc(NND);
  const size_t w_hasm    = alloc(NND);
  const size_t w_qbias   = alloc(172);
  const size_t w_relu    = alloc(172);
  const size_t w_packB   = alloc(172 * 716);
  const size_t w_b716    = alloc(716);
  const size_t w_h       = alloc((size_t)NND * 172);
  const size_t w_R1      = alloc((size_t)NND * 516);  // gi; later C716 spans R1+R2
  const size_t w_R2      = alloc((size_t)NND * 516);  // gh
  if (ws_size < off * 4) return;  // insufficient scratch -> visible failure

  int*   lastpos = I + w_lastpos;
  int*   other   = I + w_other;
  int*   edge    = I + w_edge;
  float* dtv     = F + w_dtv;
  int*   hasm    = I + w_hasm;
  float* qbias   = F + w_qbias;
  float* relu_s  = F + w_relu;
  float* packB   = F + w_packB;
  float* b716    = F + w_b716;
  float* h       = F + w_h;
  float* gi      = F + w_R1;
  float* gh      = F + w_R2;
  float* C716    = F + w_R1;                          // 716/node, fits in R1+R2 (1032)
  float* aggg    = F + w_R1 + (size_t)NND * 716;      // 172/node, still within R1+R2

  const int MB = (NND + 63) / 64;  // 1563

  init_k<<<(NND + 255) / 256, 256, 0, stream>>>(lastpos, relu_s);
  scatter_k<<<(NED + 255) / 256, 256, 0, stream>>>(sources, destinations, lastpos);
  meta_k<<<(NND + 255) / 256, 256, 0, stream>>>(lastpos, sources, destinations,
                                                timestamps, last_update,
                                                other, edge, dtv, hasm);
  qbias_k<<<1, 256, 0, stream>>>(time_b, Wq, qbias);
  packB_k<<<(172 * 716 + 255) / 256, 256, 0, stream>>>(Wq, Wk, Wv, packB);
  bias716_k<<<3, 256, 0, stream>>>(qbias, Wk, b716);

  {  // gi = msg @ Wi^T + bi   (message gathered on the fly)
    GArgs g = {memory, nullptr, edge_features, time_w, time_b, other, edge, dtv,
               gru_Wi, gru_bi, gi, nullptr, NND, 616, 516};
    gemm_k<1, 1, 0><<<dim3(MB, 9), 256, 0, stream>>>(g);
  }
  {  // gh = memory @ Wh^T + bh
    GArgs g = {memory, nullptr, nullptr, nullptr, nullptr, nullptr, nullptr, nullptr,
               gru_Wh, gru_bh, gh, nullptr, NND, 172, 516};
    gemm_k<0, 1, 0><<<dim3(MB, 9), 256, 0, stream>>>(g);
  }
  gru_k<<<((size_t)NND * 172 + 255) / 256, 256, 0, stream>>>(gi, gh, memory,
                                                             node_features, hasm, h);
  {  // C716 = h @ packB + b716   ( = [q | hk | hv | qk2] )
    GArgs g = {h, nullptr, nullptr, nullptr, nullptr, nullptr, nullptr, nullptr,
               packB, b716, C716, nullptr, NND, 172, 716};
    gemm_k<0, 0, 0><<<dim3(MB, 12), 256, 0, stream>>>(g);
  }
  attn2_k<<<NND / 4, 256, 0, stream>>>(C716, Wv, time_w, time_b,
                                       neighbor_idx, neighbor_ts, timestamps, aggg);
  {  // relu_sum += sum over nodes!=0 of relu([h|agg] @ W1 + b1)
    GArgs g = {h, aggg, nullptr, nullptr, nullptr, nullptr, nullptr, nullptr,
               W1, b1, nullptr, relu_s, NND, 344, 172};
    gemm_k<2, 0, 1><<<dim3(MB, 3), 256, 0, stream>>>(g);
  }
  head_k<<<1, 256, 0, stream>>>(relu_s, W2, b2, fc2_w, fc2_b, out);
}

// Round 3
// 2158.604 us; speedup vs baseline: 1.7674x; 1.5960x over previous
//
#include <hip/hip_runtime.h>
#include <hip/hip_bf16.h>
#include <math.h>

#define NND 100000   // nodes
#define NED 200000   // edges
#define MROWS 100096 // NND padded to 128-multiple (782 M-tiles)
// MEM=172, TD=100, K=10, MSG=616, 3*MEM=516

using bf16 = __hip_bfloat16;
using short8 = __attribute__((ext_vector_type(8))) short;
using f32x4  = __attribute__((ext_vector_type(4))) float;

typedef __attribute__((address_space(3))) void lds_t;
typedef __attribute__((address_space(1))) const void gv_t;
__device__ __forceinline__ void gl16(const void* g, void* l) {
  __builtin_amdgcn_global_load_lds((gv_t*)g, (lds_t*)l, 16, 0, 0);
}

// ---------------------------------------------------------------- small kernels

__global__ void init_k(int* lastpos, float* relu_sum) {
  int i = blockIdx.x * 256 + threadIdx.x;
  if (i < NND) lastpos[i] = -1;
  if (i < 172) relu_sum[i] = 0.f;
}

__global__ void scatter_k(const int* __restrict__ src, const int* __restrict__ dst,
                          int* lastpos) {
  int e = blockIdx.x * 256 + threadIdx.x;
  if (e < NED) {
    atomicMax(&lastpos[src[e]], e);
    atomicMax(&lastpos[dst[e]], NED + e);
  }
}

__global__ void meta_k(const int* __restrict__ lastpos,
                       const int* __restrict__ src, const int* __restrict__ dst,
                       const float* __restrict__ ts, const float* __restrict__ last_update,
                       int* other, int* edge, float* dtv, int* hasm) {
  int n = blockIdx.x * 256 + threadIdx.x;
  if (n >= NND) return;
  int p = lastpos[n];
  int oth = n, e = 0, hm = 0;
  float d = 0.f;
  if (p >= 0) {
    hm = 1;
    if (p >= NED) { e = p - NED; oth = src[e]; }   // node was destination
    else          { e = p;       oth = dst[e]; }   // node was source
    d = ts[e] - last_update[n];
  }
  other[n] = oth; edge[n] = e; dtv[n] = d; hasm[n] = hm;
}

__global__ void qbias_k(const float* __restrict__ tb, const float* __restrict__ Wq,
                        float* qbias) {
  int o = threadIdx.x;
  if (o < 172) {
    float s = 0.f;
    for (int d = 0; d < 100; d++) s += cosf(tb[d]) * Wq[(172 + d) * 172 + o];
    qbias[o] = s;
  }
}

// bias for the 716 proj cols: [qbias | 0(344) | qk2-const]
__global__ void bias716_k(const float* __restrict__ qbias, const float* __restrict__ Wk,
                          float* bias) {
  int o = blockIdx.x * 256 + threadIdx.x;
  if (o >= 716) return;
  float v = 0.f;
  if (o < 172) v = qbias[o];
  else if (o >= 516) {
    int p = o - 516, hh = p / 100, d = p - hh * 100;
    const float* qb  = qbias + hh * 86;
    const float* wk2 = Wk + (172 + d) * 172 + hh * 86;
    float s = 0.f;
    for (int cc = 0; cc < 86; cc++) s = fmaf(qb[cc], wk2[cc], s);
    v = s;
  }
  bias[o] = v;
}

// f32 -> bf16 weight convert with zero padding; transp: src is [s x r], dst[o][k]=src[k][o]
__global__ void cvtW_k(const float* __restrict__ src, bf16* __restrict__ dst,
                       int R, int S, int r, int s, int transp) {
  int i = blockIdx.x * 256 + threadIdx.x;
  if (i >= R * S) return;
  int rr = i / S, cc = i - rr * S;
  float v = 0.f;
  if (rr < r && cc < s) v = transp ? src[(size_t)cc * r + rr] : src[(size_t)rr * s + cc];
  dst[i] = __float2bfloat16(v);
}

// packed proj weight, transposed bf16: [768 rows x 192] = [Wq | Wk | Wv | Wqk2]^T
__global__ void packBT_k(const float* __restrict__ Wq, const float* __restrict__ Wk,
                         const float* __restrict__ Wv, bf16* __restrict__ dst) {
  int i = blockIdx.x * 256 + threadIdx.x;
  if (i >= 768 * 192) return;
  int o = i / 192, c = i - o * 192;
  float v = 0.f;
  if (o < 716 && c < 172) {
    if (o < 172)      v = Wq[c * 172 + o];
    else if (o < 344) v = Wk[c * 172 + (o - 172)];
    else if (o < 516) v = Wv[c * 172 + (o - 344)];
    else {
      int p = o - 516, hh = p / 100, d = p - hh * 100;
      const float* wq  = Wq + c * 172 + hh * 86;
      const float* wk2 = Wk + (172 + d) * 172 + hh * 86;
      float s = 0.f;
      for (int cc = 0; cc < 86; cc++) s = fmaf(wq[cc], wk2[cc], s);
      v = s;
    }
  }
  dst[i] = __float2bfloat16(v);
}

// message matrix Mg [MROWS x 640] bf16, zero-padded rows/cols
__global__ void msg_k(const float* __restrict__ mem, const float* __restrict__ ef,
                      const int* __restrict__ other, const int* __restrict__ edge,
                      const float* __restrict__ dtv, const float* __restrict__ tw,
                      const float* __restrict__ tb, bf16* __restrict__ Mg) {
  int i = blockIdx.x * 256 + threadIdx.x;
  if (i >= MROWS * 640) return;
  int n = i / 640, c = i - n * 640;
  float v = 0.f;
  if (n < NND && c < 616) {
    if (c < 172)      v = mem[(size_t)n * 172 + c];
    else if (c < 344) v = mem[(size_t)other[n] * 172 + (c - 172)];
    else if (c < 516) v = ef[(size_t)edge[n] * 172 + (c - 344)];
    else              v = cosf(dtv[n] * tw[c - 516] + tb[c - 516]);
  }
  Mg[i] = __float2bfloat16(v);
}

// memory f32 -> bf16 [MROWS x 192] zero-padded
__global__ void cvtmem_k(const float* __restrict__ mem, bf16* __restrict__ dst) {
  int i = blockIdx.x * 256 + threadIdx.x;
  if (i >= MROWS * 192) return;
  int n = i / 192, c = i - n * 192;
  float v = (n < NND && c < 172) ? mem[(size_t)n * 172 + c] : 0.f;
  dst[i] = __float2bfloat16(v);
}

// GRU combine; writes hB [MROWS x 192] and hagg cols 0..171 (+ zero pads)
__global__ void gru_k(const bf16* __restrict__ gi, const bf16* __restrict__ gh,
                      const float* __restrict__ memory, const float* __restrict__ nf,
                      const int* __restrict__ hasm,
                      bf16* __restrict__ hB, bf16* __restrict__ hagg) {
  int i = blockIdx.x * 256 + threadIdx.x;
  if (i >= MROWS * 192) return;
  int n = i / 192, c = i - n * 192;
  const bf16 z16 = __float2bfloat16(0.f);
  if (n >= NND) {                       // pad rows: zero everything
    hB[i] = z16;
    hagg[(size_t)n * 384 + c] = z16;
    hagg[(size_t)n * 384 + 192 + c] = z16;
    return;
  }
  if (c >= 172) {                       // pad cols
    hB[i] = z16;
    hagg[(size_t)n * 384 + 344 + (c - 172)] = z16;
    hagg[(size_t)n * 384 + 364 + (c - 172)] = z16;
    return;
  }
  float memv = memory[(size_t)n * 172 + c];
  float hv = memv;
  if (hasm[n]) {
    const bf16* gin = gi + (size_t)n * 516;
    const bf16* ghn = gh + (size_t)n * 516;
    float r  = 1.f / (1.f + expf(-(__bfloat162float(gin[c]) + __bfloat162float(ghn[c]))));
    float z  = 1.f / (1.f + expf(-(__bfloat162float(gin[172 + c]) + __bfloat162float(ghn[172 + c]))));
    float nn = tanhf(__bfloat162float(gin[344 + c]) + r * __bfloat162float(ghn[344 + c]));
    hv = (1.f - z) * nn + z * memv;
  }
  float hout = hv + nf[(size_t)n * 172 + c];
  bf16 hb = __float2bfloat16(hout);
  hB[i] = hb;
  hagg[(size_t)n * 384 + c] = hb;
}

// ---------------------------------------------------------------- bf16 MFMA GEMM
// C[M,O] = A[M,K] @ B^T + bias, A [rows x AS] bf16 (zero-padded to MROWS/K),
// B [Orows x BS] bf16 ([O][K], zero-padded). 128x128 tile, BK=32, 4 waves.
// EPI 1: relu + column-sum (skip row 0) -> red.  EPI 2: bf16 store to Cb.
// EPI 3: proj split -> C f32 [q(0..171)|qk2(516..715 -> cols 172..371)],
//                      Cb bf16 [cols 172..515 -> 0..343].

template<int EPI>
__global__ __launch_bounds__(256) void mgemm_k(
    const bf16* __restrict__ A, int AS, const bf16* __restrict__ B, int BS,
    const float* __restrict__ bias,
    float* __restrict__ C, int CS, bf16* __restrict__ Cb, int CbS,
    float* __restrict__ red, int M, int O, int K) {
  __shared__ bf16 As[128 * 32];
  __shared__ bf16 Bs[128 * 32];
  const int tid = threadIdx.x, w = tid >> 6, lane = tid & 63;
  const int m0 = blockIdx.x * 128, o0 = blockIdx.y * 128;
  const int quad = lane >> 4, l16 = lane & 15;
  const int wm = (w & 1) * 64, wn = (w >> 1) * 64;
  f32x4 acc[4][4] = {};
  // staging addresses: wave w covers segments w*2, w*2+1 (16 rows, full 32-k each)
  const bf16* ga = A + (size_t)(m0 + w * 32 + (lane >> 2)) * AS + (lane & 3) * 8;
  const bf16* gb = B + (size_t)(o0 + w * 32 + (lane >> 2)) * BS + (lane & 3) * 8;
  bf16* lA = As + w * 1024;   // segment base (elements): seg w*2 at w*1024, +512 for r=1
  bf16* lB = Bs + w * 1024;
  for (int k0 = 0; k0 < K; k0 += 32) {
    gl16(ga, lA);               gl16(ga + (size_t)16 * AS, lA + 512);
    gl16(gb, lB);               gl16(gb + (size_t)16 * BS, lB + 512);
    ga += 32; gb += 32;
    __syncthreads();            // drains vmcnt (global_load_lds) + lgkm
    short8 af[4], bfm[4];
    #pragma unroll
    for (int i = 0; i < 4; i++)
      af[i] = *(const short8*)&As[(wm + i * 16 + l16) * 32 + quad * 8];
    #pragma unroll
    for (int j = 0; j < 4; j++)
      bfm[j] = *(const short8*)&Bs[(wn + j * 16 + l16) * 32 + quad * 8];
    #pragma unroll
    for (int i = 0; i < 4; i++)
      #pragma unroll
      for (int j = 0; j < 4; j++)
        acc[i][j] = __builtin_amdgcn_mfma_f32_16x16x32_bf16(af[i], bfm[j], acc[i][j], 0, 0, 0);
    __syncthreads();
  }
  // D layout: col = l16 (o), row = quad*4 + p (m) per 16x16 subtile [m89/m91]
  if (EPI == 2) {
    #pragma unroll
    for (int i = 0; i < 4; i++)
      #pragma unroll
      for (int p = 0; p < 4; p++) {
        const int m = m0 + wm + i * 16 + quad * 4 + p;
        if (m < M) {
          #pragma unroll
          for (int j = 0; j < 4; j++) {
            const int o = o0 + wn + j * 16 + l16;
            if (o < O) Cb[(size_t)m * CbS + o] = __float2bfloat16(acc[i][j][p] + bias[o]);
          }
        }
      }
  } else if (EPI == 3) {
    #pragma unroll
    for (int i = 0; i < 4; i++)
      #pragma unroll
      for (int p = 0; p < 4; p++) {
        const int m = m0 + wm + i * 16 + quad * 4 + p;
        if (m < M) {
          #pragma unroll
          for (int j = 0; j < 4; j++) {
            const int o = o0 + wn + j * 16 + l16;
            if (o < O) {
              const float v = acc[i][j][p] + bias[o];
              if (o < 172)      C[(size_t)m * CS + o] = v;
              else if (o < 516) Cb[(size_t)m * CbS + (o - 172)] = __float2bfloat16(v);
              else              C[(size_t)m * CS + (o - 344)] = v;
            }
          }
        }
      }
  } else {  // EPI == 1: relu + colsum (rows 1..M-1)
    __shared__ float colsum[128];
    if (tid < 128) colsum[tid] = 0.f;
    __syncthreads();
    float part[4] = {0.f, 0.f, 0.f, 0.f};
    #pragma unroll
    for (int i = 0; i < 4; i++)
      #pragma unroll
      for (int p = 0; p < 4; p++) {
        const int m = m0 + wm + i * 16 + quad * 4 + p;
        const bool valid = (m < M) && (m != 0);
        if (valid) {
          #pragma unroll
          for (int j = 0; j < 4; j++) {
            const int o = o0 + wn + j * 16 + l16;
            if (o < O) part[j] += fmaxf(acc[i][j][p] + bias[o], 0.f);
          }
        }
      }
    #pragma unroll
    for (int j = 0; j < 4; j++) atomicAdd(&colsum[wn + j * 16 + l16], part[j]);
    __syncthreads();
    if (tid < 128) {
      const int o = o0 + tid;
      if (o < O) atomicAdd(&red[o], colsum[tid]);
    }
  }
}

// ---------------------------------------------------------------- attention
// wave-per-node; q/qk2 from Cq f32 [NND x 372], hk/hv from kv bf16 [NND x 344];
// writes agg bf16 into hagg cols 172..343.
__global__ __launch_bounds__(256) void attn2_k(
    const float* __restrict__ Cq, const bf16* __restrict__ kv,
    const float* __restrict__ Wv,
    const float* __restrict__ tw, const float* __restrict__ tb,
    const int* __restrict__ nidx, const float* __restrict__ nts,
    const float* __restrict__ ts, bf16* __restrict__ hagg) {
  __shared__ float wts[4][200];
  const int w = threadIdx.x >> 6;
  const int wid = blockIdx.x * 4 + w;
  const int lane = threadIdx.x & 63;
  const float t_now = ts[NED - 1];
  const float* row = Cq + (size_t)wid * 372;

  const float q0 = row[lane];
  const float q1 = row[64 + lane];
  const float q2 = (lane < 44) ? row[128 + lane] : 0.f;
  const float k0a = row[172 + lane];
  const float k0b = (lane < 36) ? row[236 + lane] : 0.f;
  const float k1a = row[272 + lane];
  const float k1b = (lane < 36) ? row[336 + lane] : 0.f;
  const float twa = tw[lane], tba = tb[lane];
  const float twb = (lane < 36) ? tw[64 + lane] : 0.f;
  const float tbb = (lane < 36) ? tb[64 + lane] : 0.f;

  float va[10], vb[10], vc[10], ta[10], tbv[10], s0[10], s1[10];
  #pragma unroll
  for (int j = 0; j < 10; j++) {
    const int ix = nidx[wid * 10 + j];
    const float ndt = t_now - nts[wid * 10 + j];
    const float tja = cosf(ndt * twa + tba);
    const float tjb = (lane < 36) ? cosf(ndt * twb + tbb) : 0.f;
    ta[j] = tja; tbv[j] = tjb;
    const bf16* krow = kv + (size_t)ix * 344;
    const float h0 = __bfloat162float(krow[lane]);
    const float h1 = __bfloat162float(krow[64 + lane]);
    const float h2 = (lane < 44) ? __bfloat162float(krow[128 + lane]) : 0.f;
    const bf16* vrow = krow + 172;
    va[j] = __bfloat162float(vrow[lane]);
    vb[j] = __bfloat162float(vrow[64 + lane]);
    vc[j] = (lane < 44) ? __bfloat162float(vrow[128 + lane]) : 0.f;
    float p0 = q0 * h0 + tja * k0a + tjb * k0b;
    float p1 = q2 * h2 + tja * k1a + tjb * k1b;
    const float m1 = q1 * h1;
    if (lane < 22) p0 += m1; else p1 += m1;
    #pragma unroll
    for (int off = 32; off; off >>= 1) {
      p0 += __shfl_xor(p0, off);
      p1 += __shfl_xor(p1, off);
    }
    const float scale = 0.10783277320343841f;  // 1/sqrt(86)
    s0[j] = p0 * scale; s1[j] = p1 * scale;
  }
  float m0 = s0[0], m1v = s1[0];
  #pragma unroll
  for (int j = 1; j < 10; j++) { m0 = fmaxf(m0, s0[j]); m1v = fmaxf(m1v, s1[j]); }
  float z0 = 0.f, z1 = 0.f;
  #pragma unroll
  for (int j = 0; j < 10; j++) {
    s0[j] = expf(s0[j] - m0);  z0 += s0[j];
    s1[j] = expf(s1[j] - m1v); z1 += s1[j];
  }
  const float i0 = 1.f / z0, i1 = 1.f / z1;
  float o0 = 0.f, o1 = 0.f, o2 = 0.f;
  float w0a = 0.f, w0b = 0.f, w1a = 0.f, w1b = 0.f;
  #pragma unroll
  for (int j = 0; j < 10; j++) {
    const float a0 = s0[j] * i0, a1 = s1[j] * i1;
    o0 += a0 * va[j];
    o1 += ((lane < 22) ? a0 : a1) * vb[j];
    o2 += a1 * vc[j];
    w0a += a0 * ta[j]; w0b += a0 * tbv[j];
    w1a += a1 * ta[j]; w1b += a1 * tbv[j];
  }
  wts[w][lane] = w0a;
  if (lane < 36) wts[w][64 + lane] = w0b;
  wts[w][100 + lane] = w1a;
  if (lane < 36) wts[w][164 + lane] = w1b;
  __syncthreads();
  #pragma unroll 4
  for (int d = 0; d < 100; d++) {
    const float wv0 = wts[w][d], wv1 = wts[w][100 + d];
    const float* vr = Wv + (size_t)(172 + d) * 172;
    o0 = fmaf(wv0, vr[lane], o0);
    o1 = fmaf((lane < 22) ? wv0 : wv1, vr[64 + lane], o1);
    if (lane < 44) o2 = fmaf(wv1, vr[128 + lane], o2);
  }
  bf16* orow = hagg + (size_t)wid * 384 + 172;
  orow[lane] = __float2bfloat16(o0);
  orow[64 + lane] = __float2bfloat16(o1);
  if (lane < 44) orow[128 + lane] = __float2bfloat16(o2);
}

// ---------------------------------------------------------------- classifier head

__global__ void head_k(const float* __restrict__ relu_sum, const float* __restrict__ W2,
                       const float* __restrict__ b2, const float* __restrict__ fc2w,
                       const float* __restrict__ fc2b, float* out) {
  __shared__ float th[172];
  int t = threadIdx.x;
  if (t < 172) {
    float s = 0.f;
    for (int c = 0; c < 172; c++) s = fmaf(relu_sum[c], W2[c * 172 + t], s);
    s = s * (1.0f / 99999.0f) + b2[t];
    th[t] = tanhf(s);
  }
  __syncthreads();
  if (t == 0) {
    float l0 = fc2b[0], l1 = fc2b[1];
    for (int o = 0; o < 172; o++) {
      l0 = fmaf(th[o], fc2w[o * 2 + 0], l0);
      l1 = fmaf(th[o], fc2w[o * 2 + 1], l1);
    }
    float mx = fmaxf(l0, l1);
    float e0 = expf(l0 - mx), e1 = expf(l1 - mx);
    float inv = 1.f / (e0 + e1);
    out[0] = e0 * inv;
    out[1] = e1 * inv;
  }
}

// ---------------------------------------------------------------- launch

extern "C" void kernel_launch(void* const* d_in, const int* in_sizes, int n_in,
                              void* d_out, int out_size, void* d_ws, size_t ws_size,
                              hipStream_t stream) {
  (void)in_sizes; (void)n_in; (void)out_size;
  const float* node_features = (const float*)d_in[0];
  const float* memory        = (const float*)d_in[1];
  const float* last_update   = (const float*)d_in[2];
  const float* timestamps    = (const float*)d_in[3];
  const float* edge_features = (const float*)d_in[4];
  const float* neighbor_ts   = (const float*)d_in[5];
  const float* time_w        = (const float*)d_in[6];
  const float* time_b        = (const float*)d_in[7];
  const float* gru_Wi        = (const float*)d_in[8];
  const float* gru_Wh        = (const float*)d_in[9];
  const float* gru_bi        = (const float*)d_in[10];
  const float* gru_bh        = (const float*)d_in[11];
  const float* Wq            = (const float*)d_in[12];
  const float* Wk            = (const float*)d_in[13];
  const float* Wv            = (const float*)d_in[14];
  const float* W1            = (const float*)d_in[15];
  const float* b1            = (const float*)d_in[16];
  const float* W2            = (const float*)d_in[17];
  const float* b2            = (const float*)d_in[18];
  const float* fc2_w         = (const float*)d_in[19];
  const float* fc2_b         = (const float*)d_in[20];
  const int* sources         = (const int*)d_in[21];
  const int* destinations    = (const int*)d_in[22];
  const int* neighbor_idx    = (const int*)d_in[23];
  float* out = (float*)d_out;

  float* F = (float*)d_ws;
  int*   I = (int*)d_ws;
  size_t off = 0;
  auto alloc = [&off](size_t words) { size_t r = off; off += (words + 63) & ~(size_t)63; return r; };
  const size_t w_lastpos = alloc(NND);
  const size_t w_other   = alloc(NND);
  const size_t w_edge    = alloc(NND);
  const size_t w_dtv     = alloc(NND);
  const size_t w_hasm    = alloc(NND);
  const size_t w_qbias   = alloc(172);
  const size_t w_b716    = alloc(716);
  const size_t w_relu    = alloc(172);
  const size_t w_WiB     = alloc(640 * 640 / 2);
  const size_t w_WhB     = alloc(640 * 192 / 2);
  const size_t w_pBT     = alloc(768 * 192 / 2);
  const size_t w_W1T     = alloc(256 * 384 / 2);
  const size_t w_R1 = alloc((size_t)NND * 372);        // Mg bf16 (32.0M w) / Cq f32 (37.2M w)
  const size_t w_R2 = alloc((size_t)NND * 516 / 2);    // giB / kvB
  const size_t w_R3 = alloc((size_t)NND * 516 / 2);    // ghB
  const size_t w_R4 = alloc((size_t)MROWS * 192 / 2);  // memB / hB
  const size_t w_R5 = alloc((size_t)MROWS * 384 / 2);  // hagg
  if (ws_size < off * 4) return;  // insufficient scratch -> visible failure

  int*   lastpos = I + w_lastpos;
  int*   other   = I + w_other;
  int*   edge    = I + w_edge;
  float* dtv     = F + w_dtv;
  int*   hasm    = I + w_hasm;
  float* qbias   = F + w_qbias;
  float* b716    = F + w_b716;
  float* relu_s  = F + w_relu;
  bf16*  WiB     = (bf16*)(F + w_WiB);
  bf16*  WhB     = (bf16*)(F + w_WhB);
  bf16*  pBT     = (bf16*)(F + w_pBT);
  bf16*  W1T     = (bf16*)(F + w_W1T);
  bf16*  Mg      = (bf16*)(F + w_R1);
  float* Cq      = F + w_R1;
  bf16*  giB     = (bf16*)(F + w_R2);
  bf16*  kvB     = (bf16*)(F + w_R2);
  bf16*  ghB     = (bf16*)(F + w_R3);
  bf16*  memB    = (bf16*)(F + w_R4);
  bf16*  hB      = (bf16*)(F + w_R4);
  bf16*  hagg    = (bf16*)(F + w_R5);

  init_k<<<(NND + 255) / 256, 256, 0, stream>>>(lastpos, relu_s);
  scatter_k<<<(NED + 255) / 256, 256, 0, stream>>>(sources, destinations, lastpos);
  meta_k<<<(NND + 255) / 256, 256, 0, stream>>>(lastpos, sources, destinations,
                                                timestamps, last_update,
                                                other, edge, dtv, hasm);
  qbias_k<<<1, 256, 0, stream>>>(time_b, Wq, qbias);
  bias716_k<<<3, 256, 0, stream>>>(qbias, Wk, b716);
  cvtW_k<<<(640 * 640 + 255) / 256, 256, 0, stream>>>(gru_Wi, WiB, 640, 640, 516, 616, 0);
  cvtW_k<<<(640 * 192 + 255) / 256, 256, 0, stream>>>(gru_Wh, WhB, 640, 192, 516, 172, 0);
  cvtW_k<<<(256 * 384 + 255) / 256, 256, 0, stream>>>(W1, W1T, 256, 384, 172, 344, 1);
  packBT_k<<<(768 * 192 + 255) / 256, 256, 0, stream>>>(Wq, Wk, Wv, pBT);
  msg_k<<<(MROWS * 640) / 256, 256, 0, stream>>>(memory, edge_features, other, edge,
                                                 dtv, time_w, time_b, Mg);
  cvtmem_k<<<(MROWS * 192) / 256, 256, 0, stream>>>(memory, memB);

  // gi = msg @ Wi^T + bi  -> bf16
  mgemm_k<2><<<dim3(782, 5), 256, 0, stream>>>(Mg, 640, WiB, 640, gru_bi,
                                               nullptr, 0, giB, 516, nullptr,
                                               NND, 516, 640);
  // gh = memory @ Wh^T + bh -> bf16
  mgemm_k<2><<<dim3(782, 5), 256, 0, stream>>>(memB, 192, WhB, 192, gru_bh,
                                               nullptr, 0, ghB, 516, nullptr,
                                               NND, 516, 192);
  gru_k<<<(MROWS * 192) / 256, 256, 0, stream>>>(giB, ghB, memory, node_features,
                                                 hasm, hB, hagg);
  // [q|hk|hv|qk2] = h @ packB  (split epilogue: Cq f32, kv bf16)
  mgemm_k<3><<<dim3(782, 6), 256, 0, stream>>>(hB, 192, pBT, 192, b716,
                                               Cq, 372, kvB, 344, nullptr,
                                               NND, 716, 192);
  attn2_k<<<NND / 4, 256, 0, stream>>>(Cq, kvB, Wv, time_w, time_b,
                                       neighbor_idx, neighbor_ts, timestamps, hagg);
  // relu_sum += colsum(relu([h|agg] @ W1 + b1)), rows 1..N-1
  mgemm_k<1><<<dim3(782, 2), 256, 0, stream>>>(hagg, 384, W1T, 384, b1,
                                               nullptr, 0, nullptr, 0, relu_s,
                                               NND, 172, 384);
  head_k<<<1, 256, 0, stream>>>(relu_s, W2, b2, fc2_w, fc2_b, out);
}

// Round 4
// 1766.622 us; speedup vs baseline: 2.1596x; 1.2219x over previous
//
#include <hip/hip_runtime.h>
#include <hip/hip_bf16.h>
#include <math.h>

#define NND 100000   // nodes
#define NED 200000   // edges
#define MROWS 100096 // NND padded to 128-multiple (782 M-tiles)
// MEM=172, TD=100, K=10, MSG=616, 3*MEM=516

using bf16 = __hip_bfloat16;
using short8 = __attribute__((ext_vector_type(8))) short;
using f32x4  = __attribute__((ext_vector_type(4))) float;

typedef __attribute__((address_space(3))) void lds_t;
typedef __attribute__((address_space(1))) const void gv_t;
__device__ __forceinline__ void gl16(const void* g, void* l) {
  __builtin_amdgcn_global_load_lds((gv_t*)g, (lds_t*)l, 16, 0, 0);
}

__device__ __forceinline__ float bfs2f(short s) {
  union { unsigned u; float f; } v; v.u = ((unsigned)(unsigned short)s) << 16; return v.f;
}
__device__ __forceinline__ short f2bfs(float f) {
  bf16 b = __float2bfloat16(f);
  union { bf16 b; short s; } u; u.b = b; return u.s;
}

// ---------------------------------------------------------------- small kernels

__global__ void init_k(int* lastpos, float* relu_sum) {
  int i = blockIdx.x * 256 + threadIdx.x;
  if (i < NND) lastpos[i] = -1;
  if (i < 172) relu_sum[i] = 0.f;
}

__global__ void scatter_k(const int* __restrict__ src, const int* __restrict__ dst,
                          int* lastpos) {
  int e = blockIdx.x * 256 + threadIdx.x;
  if (e < NED) {
    atomicMax(&lastpos[src[e]], e);
    atomicMax(&lastpos[dst[e]], NED + e);
  }
}

__global__ void meta_k(const int* __restrict__ lastpos,
                       const int* __restrict__ src, const int* __restrict__ dst,
                       const float* __restrict__ ts, const float* __restrict__ last_update,
                       int* other, int* edge, float* dtv, int* hasm) {
  int n = blockIdx.x * 256 + threadIdx.x;
  if (n >= NND) return;
  int p = lastpos[n];
  int oth = n, e = 0, hm = 0;
  float d = 0.f;
  if (p >= 0) {
    hm = 1;
    if (p >= NED) { e = p - NED; oth = src[e]; }   // node was destination
    else          { e = p;       oth = dst[e]; }   // node was source
    d = ts[e] - last_update[n];
  }
  other[n] = oth; edge[n] = e; dtv[n] = d; hasm[n] = hm;
}

__global__ void qbias_k(const float* __restrict__ tb, const float* __restrict__ Wq,
                        float* qbias) {
  int o = threadIdx.x;
  if (o < 172) {
    float s = 0.f;
    for (int d = 0; d < 100; d++) s += cosf(tb[d]) * Wq[(172 + d) * 172 + o];
    qbias[o] = s;
  }
}

// bias for the 716 proj cols: [qbias | 0(344) | qk2-const]
__global__ void bias716_k(const float* __restrict__ qbias, const float* __restrict__ Wk,
                          float* bias) {
  int o = blockIdx.x * 256 + threadIdx.x;
  if (o >= 716) return;
  float v = 0.f;
  if (o < 172) v = qbias[o];
  else if (o >= 516) {
    int p = o - 516, hh = p / 100, d = p - hh * 100;
    const float* qb  = qbias + hh * 86;
    const float* wk2 = Wk + (172 + d) * 172 + hh * 86;
    float s = 0.f;
    for (int cc = 0; cc < 86; cc++) s = fmaf(qb[cc], wk2[cc], s);
    v = s;
  }
  bias[o] = v;
}

// f32 -> bf16 weight convert with zero padding
__global__ void cvtW_k(const float* __restrict__ src, bf16* __restrict__ dst,
                       int R, int S, int r, int s) {
  int i = blockIdx.x * 256 + threadIdx.x;
  if (i >= R * S) return;
  int rr = i / S, cc = i - rr * S;
  float v = (rr < r && cc < s) ? src[(size_t)rr * s + cc] : 0.f;
  dst[i] = __float2bfloat16(v);
}

// packed proj weight, transposed bf16: [768 rows x 192] = [Wq | Wk | Wv | Wqk2]^T
__global__ void packBT_k(const float* __restrict__ Wq, const float* __restrict__ Wk,
                         const float* __restrict__ Wv, bf16* __restrict__ dst) {
  int i = blockIdx.x * 256 + threadIdx.x;
  if (i >= 768 * 192) return;
  int o = i / 192, c = i - o * 192;
  float v = 0.f;
  if (o < 716 && c < 172) {
    if (o < 172)      v = Wq[c * 172 + o];
    else if (o < 344) v = Wk[c * 172 + (o - 172)];
    else if (o < 516) v = Wv[c * 172 + (o - 344)];
    else {
      int p = o - 516, hh = p / 100, d = p - hh * 100;
      const float* wq  = Wq + c * 172 + hh * 86;
      const float* wk2 = Wk + (172 + d) * 172 + hh * 86;
      float s = 0.f;
      for (int cc = 0; cc < 86; cc++) s = fmaf(wq[cc], wk2[cc], s);
      v = s;
    }
  }
  dst[i] = __float2bfloat16(v);
}

// extended W1 weight, transposed bf16: [256 rows x 544]
// col k<344: W1[k][o]; col 344+h*100+d: sum_{t in head h} Wv[(172+d)*172+t]*W1[(172+t)*172+o]
__global__ void packW1x_k(const float* __restrict__ W1, const float* __restrict__ Wv,
                          bf16* __restrict__ dst) {
  int i = blockIdx.x * 256 + threadIdx.x;
  if (i >= 256 * 544) return;
  int o = i / 544, k = i - o * 544;
  float v = 0.f;
  if (o < 172) {
    if (k < 344) v = W1[(size_t)k * 172 + o];
    else {
      int p = k - 344, hh = p / 100, d = p - hh * 100;
      const float* wv2 = Wv + (size_t)(172 + d) * 172;
      float s = 0.f;
      for (int t = hh * 86; t < hh * 86 + 86; t++)
        s = fmaf(wv2[t], W1[(size_t)(172 + t) * 172 + o], s);
      v = s;
    }
  }
  dst[i] = __float2bfloat16(v);
}

// message matrix Mg [MROWS x 640] bf16, zero-padded rows/cols
__global__ void msg_k(const float* __restrict__ mem, const float* __restrict__ ef,
                      const int* __restrict__ other, const int* __restrict__ edge,
                      const float* __restrict__ dtv, const float* __restrict__ tw,
                      const float* __restrict__ tb, bf16* __restrict__ Mg) {
  int i = blockIdx.x * 256 + threadIdx.x;
  if (i >= MROWS * 640) return;
  int n = i / 640, c = i - n * 640;
  float v = 0.f;
  if (n < NND && c < 616) {
    if (c < 172)      v = mem[(size_t)n * 172 + c];
    else if (c < 344) v = mem[(size_t)other[n] * 172 + (c - 172)];
    else if (c < 516) v = ef[(size_t)edge[n] * 172 + (c - 344)];
    else              v = cosf(dtv[n] * tw[c - 516] + tb[c - 516]);
  }
  Mg[i] = __float2bfloat16(v);
}

// memory f32 -> bf16 [MROWS x 192] zero-padded
__global__ void cvtmem_k(const float* __restrict__ mem, bf16* __restrict__ dst) {
  int i = blockIdx.x * 256 + threadIdx.x;
  if (i >= MROWS * 192) return;
  int n = i / 192, c = i - n * 192;
  float v = (n < NND && c < 172) ? mem[(size_t)n * 172 + c] : 0.f;
  dst[i] = __float2bfloat16(v);
}

// zero pad rows of haw (rows NND..MROWS-1, 544 cols)
__global__ void padrow_k(bf16* __restrict__ haw) {
  int i = blockIdx.x * 256 + threadIdx.x;
  if (i < (MROWS - NND) * 544) haw[(size_t)NND * 544 + i] = __float2bfloat16(0.f);
}

// GRU combine; writes hB [MROWS x 192] and haw cols 0..171
__global__ void gru_k(const bf16* __restrict__ gi, const bf16* __restrict__ gh,
                      const float* __restrict__ memory, const float* __restrict__ nf,
                      const int* __restrict__ hasm,
                      bf16* __restrict__ hB, bf16* __restrict__ haw) {
  int i = blockIdx.x * 256 + threadIdx.x;
  if (i >= MROWS * 192) return;
  int n = i / 192, c = i - n * 192;
  if (n >= NND || c >= 172) { hB[i] = __float2bfloat16(0.f); return; }
  float memv = memory[(size_t)n * 172 + c];
  float hv = memv;
  if (hasm[n]) {
    const bf16* gin = gi + (size_t)n * 516;
    const bf16* ghn = gh + (size_t)n * 516;
    float r  = 1.f / (1.f + expf(-(__bfloat162float(gin[c]) + __bfloat162float(ghn[c]))));
    float z  = 1.f / (1.f + expf(-(__bfloat162float(gin[172 + c]) + __bfloat162float(ghn[172 + c]))));
    float nn = tanhf(__bfloat162float(gin[344 + c]) + r * __bfloat162float(ghn[344 + c]));
    hv = (1.f - z) * nn + z * memv;
  }
  float hout = hv + nf[(size_t)n * 172 + c];
  bf16 hb = __float2bfloat16(hout);
  hB[i] = hb;
  haw[(size_t)n * 544 + c] = hb;
}

// ---------------------------------------------------------------- bf16 MFMA GEMM
// C[M,O] = A[M,K] @ B^T + bias. 128x128 tile, BK=32, 4 waves.
// EPI 1: relu + column-sum (skip row 0) -> red.  EPI 2: bf16 store to Cb.
// EPI 3: proj split -> C f32 [q | qk2->cols 172..371], Cb bf16 [cols 172..515 -> 0..343].

template<int EPI>
__global__ __launch_bounds__(256) void mgemm_k(
    const bf16* __restrict__ A, int AS, const bf16* __restrict__ B, int BS,
    const float* __restrict__ bias,
    float* __restrict__ C, int CS, bf16* __restrict__ Cb, int CbS,
    float* __restrict__ red, int M, int O, int K) {
  __shared__ bf16 As[128 * 32];
  __shared__ bf16 Bs[128 * 32];
  const int tid = threadIdx.x, w = tid >> 6, lane = tid & 63;
  const int m0 = blockIdx.x * 128, o0 = blockIdx.y * 128;
  const int quad = lane >> 4, l16 = lane & 15;
  const int wm = (w & 1) * 64, wn = (w >> 1) * 64;
  f32x4 acc[4][4] = {};
  const bf16* ga = A + (size_t)(m0 + w * 32 + (lane >> 2)) * AS + (lane & 3) * 8;
  const bf16* gb = B + (size_t)(o0 + w * 32 + (lane >> 2)) * BS + (lane & 3) * 8;
  bf16* lA = As + w * 1024;
  bf16* lB = Bs + w * 1024;
  for (int k0 = 0; k0 < K; k0 += 32) {
    gl16(ga, lA);               gl16(ga + (size_t)16 * AS, lA + 512);
    gl16(gb, lB);               gl16(gb + (size_t)16 * BS, lB + 512);
    ga += 32; gb += 32;
    __syncthreads();
    short8 af[4], bfm[4];
    #pragma unroll
    for (int i = 0; i < 4; i++)
      af[i] = *(const short8*)&As[(wm + i * 16 + l16) * 32 + quad * 8];
    #pragma unroll
    for (int j = 0; j < 4; j++)
      bfm[j] = *(const short8*)&Bs[(wn + j * 16 + l16) * 32 + quad * 8];
    #pragma unroll
    for (int i = 0; i < 4; i++)
      #pragma unroll
      for (int j = 0; j < 4; j++)
        acc[i][j] = __builtin_amdgcn_mfma_f32_16x16x32_bf16(af[i], bfm[j], acc[i][j], 0, 0, 0);
    __syncthreads();
  }
  if (EPI == 2) {
    #pragma unroll
    for (int i = 0; i < 4; i++)
      #pragma unroll
      for (int p = 0; p < 4; p++) {
        const int m = m0 + wm + i * 16 + quad * 4 + p;
        if (m < M) {
          #pragma unroll
          for (int j = 0; j < 4; j++) {
            const int o = o0 + wn + j * 16 + l16;
            if (o < O) Cb[(size_t)m * CbS + o] = __float2bfloat16(acc[i][j][p] + bias[o]);
          }
        }
      }
  } else if (EPI == 3) {
    #pragma unroll
    for (int i = 0; i < 4; i++)
      #pragma unroll
      for (int p = 0; p < 4; p++) {
        const int m = m0 + wm + i * 16 + quad * 4 + p;
        if (m < M) {
          #pragma unroll
          for (int j = 0; j < 4; j++) {
            const int o = o0 + wn + j * 16 + l16;
            if (o < O) {
              const float v = acc[i][j][p] + bias[o];
              if (o < 172)      C[(size_t)m * CS + o] = v;
              else if (o < 516) Cb[(size_t)m * CbS + (o - 172)] = __float2bfloat16(v);
              else              C[(size_t)m * CS + (o - 344)] = v;
            }
          }
        }
      }
  } else {  // EPI == 1: relu + colsum (rows 1..M-1)
    __shared__ float colsum[128];
    if (tid < 128) colsum[tid] = 0.f;
    __syncthreads();
    float part[4] = {0.f, 0.f, 0.f, 0.f};
    #pragma unroll
    for (int i = 0; i < 4; i++)
      #pragma unroll
      for (int p = 0; p < 4; p++) {
        const int m = m0 + wm + i * 16 + quad * 4 + p;
        const bool valid = (m < M) && (m != 0);
        if (valid) {
          #pragma unroll
          for (int j = 0; j < 4; j++) {
            const int o = o0 + wn + j * 16 + l16;
            if (o < O) part[j] += fmaxf(acc[i][j][p] + bias[o], 0.f);
          }
        }
      }
    #pragma unroll
    for (int j = 0; j < 4; j++) atomicAdd(&colsum[wn + j * 16 + l16], part[j]);
    __syncthreads();
    if (tid < 128) {
      const int o = o0 + tid;
      if (o < O) atomicAdd(&red[o], colsum[tid]);
    }
  }
}

// ---------------------------------------------------------------- attention v3
// Wave per node, no LDS, no barrier. kv gathers are one dwordx4 per neighbor
// (lane l<43 owns row elems 8l..8l+7 of [hk(172)|hv(172)]). Writes aggv (cols
// 172..343) and wt (cols 344..543) of haw; the wt@Wv2 term is folded into the
// W1 GEMM via packW1x.
__global__ __launch_bounds__(256) void attn3_k(
    const float* __restrict__ Cq, const bf16* __restrict__ kv,
    const float* __restrict__ tw, const float* __restrict__ tb,
    const int* __restrict__ nidx, const float* __restrict__ nts,
    const float* __restrict__ ts, bf16* __restrict__ haw) {
  const int w = threadIdx.x >> 6, lane = threadIdx.x & 63;
  const int wid = blockIdx.x * 4 + w;
  const float t_now = ts[NED - 1];
  const float* row = Cq + (size_t)wid * 372;

  // q chunk pre-masked by head: qs0 = q * [e<86], qs1 = q * [86<=e<172]
  float qs0[8], qs1[8];
  {
    float qc[8];
    if (lane < 22) {
      float4 a = *(const float4*)(row + 8 * lane);
      float4 b = *(const float4*)(row + 8 * lane + 4);
      qc[0] = a.x; qc[1] = a.y; qc[2] = a.z; qc[3] = a.w;
      qc[4] = b.x; qc[5] = b.y; qc[6] = b.z; qc[7] = b.w;
    } else {
      #pragma unroll
      for (int p = 0; p < 8; p++) qc[p] = 0.f;
    }
    #pragma unroll
    for (int p = 0; p < 8; p++) {
      const int e = 8 * lane + p;
      qs0[p] = (e < 86) ? qc[p] : 0.f;
      qs1[p] = (e >= 86 && e < 172) ? qc[p] : 0.f;
    }
  }
  const float k0a = row[172 + lane];
  const float k0b = (lane < 36) ? row[236 + lane] : 0.f;
  const float k1a = row[272 + lane];
  const float k1b = (lane < 36) ? row[336 + lane] : 0.f;
  const float twa = tw[lane], tba = tb[lane];
  const float twb = (lane < 36) ? tw[64 + lane] : 0.f;
  const float tbb = (lane < 36) ? tb[64 + lane] : 0.f;

  short8 kvc[10];
  float ta[10], tbv[10], s0[10], s1[10];
  #pragma unroll
  for (int j = 0; j < 10; j++) {
    const int ix = nidx[wid * 10 + j];
    const float ndt = t_now - nts[wid * 10 + j];
    const float tja = cosf(ndt * twa + tba);
    const float tjb = (lane < 36) ? cosf(ndt * twb + tbb) : 0.f;
    ta[j] = tja; tbv[j] = tjb;
    short8 c = {0, 0, 0, 0, 0, 0, 0, 0};
    if (lane < 43) c = *(const short8*)(kv + (size_t)ix * 344 + 8 * lane);
    kvc[j] = c;
    float p0 = tja * k0a + tjb * k0b;
    float p1 = tja * k1a + tjb * k1b;
    #pragma unroll
    for (int p = 0; p < 8; p++) {
      const float hvv = bfs2f(c[p]);
      p0 = fmaf(qs0[p], hvv, p0);
      p1 = fmaf(qs1[p], hvv, p1);
    }
    #pragma unroll
    for (int off = 32; off; off >>= 1) {
      p0 += __shfl_xor(p0, off);
      p1 += __shfl_xor(p1, off);
    }
    const float scale = 0.10783277320343841f;  // 1/sqrt(86)
    s0[j] = p0 * scale; s1[j] = p1 * scale;
  }
  // softmax per head (redundant per-lane, registers only)
  float m0 = s0[0], m1v = s1[0];
  #pragma unroll
  for (int j = 1; j < 10; j++) { m0 = fmaxf(m0, s0[j]); m1v = fmaxf(m1v, s1[j]); }
  float z0 = 0.f, z1 = 0.f;
  #pragma unroll
  for (int j = 0; j < 10; j++) {
    s0[j] = expf(s0[j] - m0);  z0 += s0[j];
    s1[j] = expf(s1[j] - m1v); z1 += s1[j];
  }
  const float i0 = 1.f / z0, i1 = 1.f / z1;
  // agg (both-head accumulate, select at store) + wt accumulation
  float av0[8] = {}, av1[8] = {};
  float w0a = 0.f, w0b = 0.f, w1a = 0.f, w1b = 0.f;
  #pragma unroll
  for (int j = 0; j < 10; j++) {
    const float a0 = s0[j] * i0, a1 = s1[j] * i1;
    #pragma unroll
    for (int p = 0; p < 8; p++) {
      const float hvv = bfs2f(kvc[j][p]);
      av0[p] = fmaf(a0, hvv, av0[p]);
      av1[p] = fmaf(a1, hvv, av1[p]);
    }
    w0a = fmaf(a0, ta[j], w0a); w0b = fmaf(a0, tbv[j], w0b);
    w1a = fmaf(a1, ta[j], w1a); w1b = fmaf(a1, tbv[j], w1b);
  }
  bf16* hrow = haw + (size_t)wid * 544;
  if (lane >= 22 && lane < 43) {        // aggv cols 8*lane .. 8*lane+7 (176..343)
    short8 st;
    #pragma unroll
    for (int p = 0; p < 8; p++) {
      const int e = 8 * lane + p;
      st[p] = f2bfs((e < 258) ? av0[p] : av1[p]);
    }
    *(short8*)(hrow + 8 * lane) = st;
  } else if (lane == 21) {              // aggv cols 172..175 (positions 4..7)
    #pragma unroll
    for (int p = 4; p < 8; p++) hrow[168 + p] = __float2bfloat16(av0[p]);
  }
  // wt: cols 344..543 = [head0 d0..99 | head1 d0..99]
  hrow[344 + lane] = __float2bfloat16(w0a);
  if (lane < 36) hrow[408 + lane] = __float2bfloat16(w0b);
  hrow[444 + lane] = __float2bfloat16(w1a);
  if (lane < 36) hrow[508 + lane] = __float2bfloat16(w1b);
}

// ---------------------------------------------------------------- classifier head

__global__ void head_k(const float* __restrict__ relu_sum, const float* __restrict__ W2,
                       const float* __restrict__ b2, const float* __restrict__ fc2w,
                       const float* __restrict__ fc2b, float* out) {
  __shared__ float th[172];
  int t = threadIdx.x;
  if (t < 172) {
    float s = 0.f;
    for (int c = 0; c < 172; c++) s = fmaf(relu_sum[c], W2[c * 172 + t], s);
    s = s * (1.0f / 99999.0f) + b2[t];
    th[t] = tanhf(s);
  }
  __syncthreads();
  if (t == 0) {
    float l0 = fc2b[0], l1 = fc2b[1];
    for (int o = 0; o < 172; o++) {
      l0 = fmaf(th[o], fc2w[o * 2 + 0], l0);
      l1 = fmaf(th[o], fc2w[o * 2 + 1], l1);
    }
    float mx = fmaxf(l0, l1);
    float e0 = expf(l0 - mx), e1 = expf(l1 - mx);
    float inv = 1.f / (e0 + e1);
    out[0] = e0 * inv;
    out[1] = e1 * inv;
  }
}

// ---------------------------------------------------------------- launch

extern "C" void kernel_launch(void* const* d_in, const int* in_sizes, int n_in,
                              void* d_out, int out_size, void* d_ws, size_t ws_size,
                              hipStream_t stream) {
  (void)in_sizes; (void)n_in; (void)out_size;
  const float* node_features = (const float*)d_in[0];
  const float* memory        = (const float*)d_in[1];
  const float* last_update   = (const float*)d_in[2];
  const float* timestamps    = (const float*)d_in[3];
  const float* edge_features = (const float*)d_in[4];
  const float* neighbor_ts   = (const float*)d_in[5];
  const float* time_w        = (const float*)d_in[6];
  const float* time_b        = (const float*)d_in[7];
  const float* gru_Wi        = (const float*)d_in[8];
  const float* gru_Wh        = (const float*)d_in[9];
  const float* gru_bi        = (const float*)d_in[10];
  const float* gru_bh        = (const float*)d_in[11];
  const float* Wq            = (const float*)d_in[12];
  const float* Wk            = (const float*)d_in[13];
  const float* Wv            = (const float*)d_in[14];
  const float* W1            = (const float*)d_in[15];
  const float* b1            = (const float*)d_in[16];
  const float* W2            = (const float*)d_in[17];
  const float* b2            = (const float*)d_in[18];
  const float* fc2_w         = (const float*)d_in[19];
  const float* fc2_b         = (const float*)d_in[20];
  const int* sources         = (const int*)d_in[21];
  const int* destinations    = (const int*)d_in[22];
  const int* neighbor_idx    = (const int*)d_in[23];
  float* out = (float*)d_out;

  float* F = (float*)d_ws;
  int*   I = (int*)d_ws;
  size_t off = 0;
  auto alloc = [&off](size_t words) { size_t r = off; off += (words + 63) & ~(size_t)63; return r; };
  const size_t w_lastpos = alloc(NND);
  const size_t w_other   = alloc(NND);
  const size_t w_edge    = alloc(NND);
  const size_t w_dtv     = alloc(NND);
  const size_t w_hasm    = alloc(NND);
  const size_t w_qbias   = alloc(172);
  const size_t w_b716    = alloc(716);
  const size_t w_relu    = alloc(172);
  const size_t w_WiB     = alloc(640 * 640 / 2);
  const size_t w_WhB     = alloc(640 * 192 / 2);
  const size_t w_pBT     = alloc(768 * 192 / 2);
  const size_t w_W1x     = alloc(256 * 544 / 2);
  const size_t w_R1 = alloc((size_t)NND * 372);        // Mg bf16 -> ghB bf16 -> Cq f32
  const size_t w_R2 = alloc((size_t)NND * 516 / 2);    // giB -> kvB
  const size_t w_R4 = alloc((size_t)MROWS * 192 / 2);  // memB -> hB
  const size_t w_R5 = alloc((size_t)MROWS * 544 / 2);  // haw [h|aggv|wt]
  if (ws_size < off * 4) return;  // insufficient scratch -> visible failure

  int*   lastpos = I + w_lastpos;
  int*   other   = I + w_other;
  int*   edge    = I + w_edge;
  float* dtv     = F + w_dtv;
  int*   hasm    = I + w_hasm;
  float* qbias   = F + w_qbias;
  float* b716    = F + w_b716;
  float* relu_s  = F + w_relu;
  bf16*  WiB     = (bf16*)(F + w_WiB);
  bf16*  WhB     = (bf16*)(F + w_WhB);
  bf16*  pBT     = (bf16*)(F + w_pBT);
  bf16*  W1x     = (bf16*)(F + w_W1x);
  bf16*  Mg      = (bf16*)(F + w_R1);
  bf16*  ghB     = (bf16*)(F + w_R1);   // after Mg is dead
  float* Cq      = F + w_R1;            // after ghB is dead
  bf16*  giB     = (bf16*)(F + w_R2);
  bf16*  kvB     = (bf16*)(F + w_R2);   // after giB is dead
  bf16*  memB    = (bf16*)(F + w_R4);
  bf16*  hB      = (bf16*)(F + w_R4);   // after memB is dead
  bf16*  haw     = (bf16*)(F + w_R5);

  init_k<<<(NND + 255) / 256, 256, 0, stream>>>(lastpos, relu_s);
  scatter_k<<<(NED + 255) / 256, 256, 0, stream>>>(sources, destinations, lastpos);
  meta_k<<<(NND + 255) / 256, 256, 0, stream>>>(lastpos, sources, destinations,
                                                timestamps, last_update,
                                                other, edge, dtv, hasm);
  qbias_k<<<1, 256, 0, stream>>>(time_b, Wq, qbias);
  bias716_k<<<3, 256, 0, stream>>>(qbias, Wk, b716);
  cvtW_k<<<(640 * 640 + 255) / 256, 256, 0, stream>>>(gru_Wi, WiB, 640, 640, 516, 616);
  cvtW_k<<<(640 * 192 + 255) / 256, 256, 0, stream>>>(gru_Wh, WhB, 640, 192, 516, 172);
  packBT_k<<<(768 * 192 + 255) / 256, 256, 0, stream>>>(Wq, Wk, Wv, pBT);
  packW1x_k<<<(256 * 544 + 255) / 256, 256, 0, stream>>>(W1, Wv, W1x);
  msg_k<<<(MROWS * 640) / 256, 256, 0, stream>>>(memory, edge_features, other, edge,
                                                 dtv, time_w, time_b, Mg);
  cvtmem_k<<<(MROWS * 192) / 256, 256, 0, stream>>>(memory, memB);
  padrow_k<<<((MROWS - NND) * 544 + 255) / 256, 256, 0, stream>>>(haw);

  // gi = msg @ Wi^T + bi  -> bf16
  mgemm_k<2><<<dim3(782, 5), 256, 0, stream>>>(Mg, 640, WiB, 640, gru_bi,
                                               nullptr, 0, giB, 516, nullptr,
                                               NND, 516, 640);
  // gh = memory @ Wh^T + bh -> bf16 (into R1; Mg dead now)
  mgemm_k<2><<<dim3(782, 5), 256, 0, stream>>>(memB, 192, WhB, 192, gru_bh,
                                               nullptr, 0, ghB, 516, nullptr,
                                               NND, 516, 192);
  gru_k<<<(MROWS * 192) / 256, 256, 0, stream>>>(giB, ghB, memory, node_features,
                                                 hasm, hB, haw);
  // [q|hk|hv|qk2] = h @ packB  (split epilogue: Cq f32, kvB bf16)
  mgemm_k<3><<<dim3(782, 6), 256, 0, stream>>>(hB, 192, pBT, 192, b716,
                                               Cq, 372, kvB, 344, nullptr,
                                               NND, 716, 192);
  attn3_k<<<NND / 4, 256, 0, stream>>>(Cq, kvB, time_w, time_b,
                                       neighbor_idx, neighbor_ts, timestamps, haw);
  // relu_sum += colsum(relu([h|aggv|wt] @ W1x + b1)), rows 1..N-1
  mgemm_k<1><<<dim3(782, 2), 256, 0, stream>>>(haw, 544, W1x, 544, b1,
                                               nullptr, 0, nullptr, 0, relu_s,
                                               NND, 172, 544);
  head_k<<<1, 256, 0, stream>>>(relu_s, W2, b2, fc2_w, fc2_b, out);
}